// Round 7
// baseline (17788.144 us; speedup 1.0000x reference)
//
#include <hip/hip_runtime.h>
#include <math.h>

// Problem constants
#define BB  64
#define TT  512
#define IN  64
#define HH  512
#define ZHH 128
#define NT  1024

// ---- ws layout (byte offsets) ----
#define OFF_EXIH   0u          // f32 [64][768]
#define OFF_EXH    196608u     // f32 [64][512]
#define OFF_FLAG   327680u     // 2*64 ints, 64B stride
#define OFF_WH     335872u     // bf16 [q<4][k8<64][384][8]
#define OFF_WX     1908736u    // bf16 [q<4][k8<8][384][8]
#define OFF_DW     2105344u    // bf16 [q<4][k8<4][1152][8]
#define OFF_X2H    2400256u    // bf16 [q<4][k8<72][96][8]
#define OFF_H2HB   2842624u    // bf16 [q<4][k8<16][96][8]
#define OFF_ZWB    2940928u    // bf16 [k8<16][288][8]
#define WS_NOX2H   2400256u
#define WS_FULL    2842624u
#define WS_XTRA    3014656u

__device__ __forceinline__ float sigmoidf_(float x) {
    return 1.0f / (1.0f + __expf(-x));
}
__device__ __forceinline__ float tanhf_(float x) {
    return 2.0f / (1.0f + __expf(-2.0f * x)) - 1.0f;
}
__device__ __forceinline__ float bflo(unsigned u) { return __uint_as_float(u << 16); }
__device__ __forceinline__ float bfhi(unsigned u) { return __uint_as_float(u & 0xffff0000u); }
__device__ __forceinline__ unsigned short f2bf(float f) {
    unsigned u = __float_as_uint(f);
    return (unsigned short)((u + 0x7fffu + ((u >> 16) & 1u)) >> 16);
}
__device__ __forceinline__ float dotbf8(uint4 U, float4 a, float4 b) {
    return bflo(U.x)*a.x + bfhi(U.x)*a.y + bflo(U.y)*a.z + bfhi(U.y)*a.w
         + bflo(U.z)*b.x + bfhi(U.z)*b.y + bflo(U.w)*b.z + bfhi(U.w)*b.w;
}
__device__ __forceinline__ float dot4_(const float4 a, const float4 b) {
    return a.x*b.x + a.y*b.y + a.z*b.z + a.w*b.w;
}
__device__ __forceinline__ uint4 packbf8(const float* s) {
    float4 a = *(const float4*)s;
    float4 c = *(const float4*)(s + 4);
    uint4 q;
    q.x = (unsigned)f2bf(a.x) | ((unsigned)f2bf(a.y) << 16);
    q.y = (unsigned)f2bf(a.z) | ((unsigned)f2bf(a.w) << 16);
    q.z = (unsigned)f2bf(c.x) | ((unsigned)f2bf(c.y) << 16);
    q.w = (unsigned)f2bf(c.z) | ((unsigned)f2bf(c.w) << 16);
    return q;
}

// ---------- pre-pass: quarter-sliced bf16 repack (identical to R5) ----------
__global__ __launch_bounds__(256)
void pack_w(const float* __restrict__ wh, const float* __restrict__ wx,
            const float* __restrict__ dh_w, const float* __restrict__ dx_w,
            const float* __restrict__ db_w, const float* __restrict__ x2h_w,
            const float* __restrict__ h2h_w, const float* __restrict__ zh_w,
            const float* __restrict__ zx_w, const float* __restrict__ zb_w,
            int packX2H, int packHZ, char* __restrict__ wsb)
{
    const int u = blockIdx.x * 256 + threadIdx.x;
    if (u < 98304) {                                   // WH
        int q = u / 24576, r1 = u % 24576, k8 = r1 / 384, rr = r1 % 384;
        int g = rr >> 7, hl = rr & 127, h = q*128 + hl;
        ((uint4*)(wsb + OFF_WH))[u] = packbf8(wh + ((size_t)(g*512 + h))*512 + k8*8);
    } else if (u < 110592) {                           // WX
        int v = u - 98304;
        int q = v / 3072, r1 = v % 3072, k8 = r1 / 384, rr = r1 % 384;
        int g = rr >> 7, hl = rr & 127, h = q*128 + hl;
        ((uint4*)(wsb + OFF_WX))[v] = packbf8(wx + ((size_t)(g*512 + h))*64 + k8*8);
    } else if (u < 129024) {                           // DW
        int v = u - 110592;
        int q = v / 4608, r1 = v % 4608, k8 = r1 / 1152, rr = r1 % 1152;
        int u9 = rr >> 7, hl = rr & 127, h = q*128 + hl;
        int kind = u9 / 3, l = u9 - kind*3;
        const float* dsrc = (kind == 0) ? dh_w : ((kind == 1) ? dx_w : db_w);
        ((uint4*)(wsb + OFF_DW))[v] = packbf8(dsrc + ((size_t)(l*512) + h)*32 + k8*8);
    } else if (u < 156672) {                           // X2H
        if (!packX2H) return;
        int v = u - 129024;
        int q = v / 6912, r1 = v % 6912, k8 = r1 / 96, rr = r1 % 96;
        int g = rr >> 5, zz = rr & 31, j = g*128 + q*32 + zz;
        ((uint4*)(wsb + OFF_X2H))[v] = packbf8(x2h_w + (size_t)j*576 + k8*8);
    } else if (u < 162816) {                           // H2HB
        if (!packHZ) return;
        int v = u - 156672;
        int q = v / 1536, r1 = v % 1536, k8 = r1 / 96, rr = r1 % 96;
        int g = rr >> 5, zz = rr & 31, j = g*128 + q*32 + zz;
        ((uint4*)(wsb + OFF_H2HB))[v] = packbf8(h2h_w + (size_t)j*128 + k8*8);
    } else if (u < 167424) {                           // ZWB
        if (!packHZ) return;
        int v = u - 162816;
        int k8 = v / 288, r = v % 288;
        const float* src = (r < 96) ? (zh_w + (size_t)r*128)
                         : ((r < 192) ? (zx_w + (size_t)(r - 96)*128)
                                      : (zb_w + (size_t)(r - 192)*128));
        ((uint4*)(wsb + OFF_ZWB))[v] = packbf8(src + k8*8);
    }
}

// ---------- main: 256 WGs = 64 batches x 4 quarters; early-publish syncs ----------
// Sibling mapping b=blk&63, q=blk>>6 keeps the 4 cooperating WGs of a batch on
// the SAME XCD under round-robin dispatch (64 == 0 mod 8) — proven in R5, and
// gives intra-L2 flag/exchange RTT. Correctness never depends on placement.
template<int X2HP, int HZP>
__global__ __launch_bounds__(NT)
void hypercell_q(
    const float* __restrict__ xs, const float* __restrict__ cond,
    const float* __restrict__ h_c, const float* __restrict__ h_c_hat,
    const float* __restrict__ x2h_w, const float* __restrict__ x2h_b,
    const float* __restrict__ h2h_w, const float* __restrict__ h2h_b,
    const float* __restrict__ zh_w, const float* __restrict__ zh_b,
    const float* __restrict__ zx_w, const float* __restrict__ zx_b,
    const float* __restrict__ zb_w, const float* __restrict__ db_b,
    char* __restrict__ wsb, float* __restrict__ out)
{
    __shared__ __align__(16) float sh_h[512];
    __shared__ __align__(16) float sh_hat[128];
    __shared__ __align__(16) float sh_x[64];
    __shared__ __align__(16) float sh_c[64];
    __shared__ __align__(16) float sh_z[288];
    __shared__ float sh_whhp[768];   // [half][384]
    __shared__ float sh_wxx[384];
    __shared__ float sh_ihp[768];    // [row][8] partials
    __shared__ float sh_hhp[192];    // [row][2] partials
    __shared__ float sh_ihhh[768];   // preloaded exchange
    __shared__ float sh_d[1152];
    __shared__ float sh_bih[96];
    __shared__ float sh_bhh[96];
    __shared__ float sh_bz[288];
    __shared__ float sh_bdb[384];

    const int b   = blockIdx.x & 63;     // batch
    const int q   = blockIdx.x >> 6;     // row quarter (siblings same XCD)
    const int tid = threadIdx.x;
    const int lane = tid & 63;

    const uint4* WHq   = (const uint4*)(wsb + OFF_WH)   + q*24576;
    const uint4* WXq   = (const uint4*)(wsb + OFF_WX)   + q*3072;
    const uint4* DWq   = (const uint4*)(wsb + OFF_DW)   + q*4608;
    const uint4* X2Hq  = (const uint4*)(wsb + OFF_X2H)  + q*6912;
    const uint4* H2HBq = (const uint4*)(wsb + OFF_H2HB) + q*1536;
    const uint4* ZWB   = (const uint4*)(wsb + OFF_ZWB);

    float* exch_ihhh = (float*)(wsb + OFF_EXIH) + (size_t)b*768;
    float* exch_h    = (float*)(wsb + OFF_EXH)  + (size_t)b*512;
    int* flagA = (int*)(wsb + OFF_FLAG + (size_t)b*64);
    int* flagB = (int*)(wsb + OFF_FLAG + 4096 + (size_t)b*64);

    // ---- init staging ----
    if (tid < 96) {
        int j = (tid >> 5)*128 + q*32 + (tid & 31);
        sh_bih[tid] = x2h_b[j];
        sh_bhh[tid] = h2h_b[j];
    }
    if (tid < 288) sh_bz[tid] = (tid < 96) ? zh_b[tid]
                              : ((tid < 192) ? zx_b[tid - 96] : 0.f);
    if (tid < 384) {
        int l = tid >> 7, hl = tid & 127;
        sh_bdb[tid] = db_b[l*512 + q*128 + hl];
    }
    if (tid < 512) sh_h[tid] = h_c[(size_t)b*512 + tid];
    if (tid < 128) sh_hat[tid] = h_c_hat[(size_t)b*128 + tid];
    if (tid < 64) {
        sh_c[tid] = cond[(size_t)b*64 + tid];
        sh_x[tid] = xs[(size_t)b*TT*IN + tid];
    }
    __syncthreads();
    // wxx for t=0
    if (tid < 384) {
        float a1 = 0.f;
        const uint4* X0 = WXq + tid;
        const float4* x4 = (const float4*)sh_x;
        #pragma unroll
        for (int k8 = 0; k8 < 8; ++k8)
            a1 += dotbf8(X0[k8*384], x4[2*k8], x4[2*k8 + 1]);
        sh_wxx[tid] = a1;
    }
    __syncthreads();

    for (int t = 0; t < TT; ++t) {
        const float4* h4   = (const float4*)sh_h;
        const float4* hat4 = (const float4*)sh_hat;
        const float4* c4   = (const float4*)sh_c;

        // ===== S1: ih/hh K-split partials (early, on old state) =====
        if (tid < 768) {
            const int rr = tid >> 3, p = tid & 7;   // 96 rows x 8 parts
            float a = 0.f;
            if (X2HP) {
                const uint4* W0 = X2Hq + rr;
                #pragma unroll
                for (int k8 = 9*p; k8 < 9*p + 9; ++k8) {
                    if (k8 < 64) a += dotbf8(W0[k8*96], h4[2*k8], h4[2*k8 + 1]);
                    else         a += dotbf8(W0[k8*96], c4[2*(k8-64)], c4[2*(k8-64) + 1]);
                }
            } else {
                const int j = (rr >> 5)*128 + q*32 + (rr & 31);
                const float4* wr = (const float4*)(x2h_w + (size_t)j*576);
                #pragma unroll
                for (int k4 = 18*p; k4 < 18*p + 18; ++k4) {
                    if (k4 < 128) a += dot4_(wr[k4], h4[k4]);
                    else          a += dot4_(wr[k4], c4[k4 - 128]);
                }
            }
            sh_ihp[rr*8 + p] = a;
        } else if (tid < 960) {
            const int u = tid - 768;
            const int rr = u >> 1, p = u & 1;       // 96 rows x 2 parts
            float a = 0.f;
            if (HZP) {
                const uint4* W = H2HBq + rr;
                #pragma unroll
                for (int k8 = 8*p; k8 < 8*p + 8; ++k8)
                    a += dotbf8(W[k8*96], hat4[2*k8], hat4[2*k8 + 1]);
            } else {
                const int j = (rr >> 5)*128 + q*32 + (rr & 31);
                const float4* wr = (const float4*)(h2h_w + (size_t)j*128);
                #pragma unroll
                for (int k4 = 16*p; k4 < 16*p + 16; ++k4)
                    a += dot4_(wr[k4], hat4[k4]);
            }
            sh_hhp[rr*2 + p] = a;
        }
        __syncthreads();

        // ===== S2: reduce + publish ih/hh =====
        if (tid < 96) {
            const int j = (tid >> 5)*128 + q*32 + (tid & 31);
            float a = sh_bih[tid];
            #pragma unroll
            for (int p = 0; p < 8; ++p) a += sh_ihp[tid*8 + p];
            __hip_atomic_store(&exch_ihhh[j], a, __ATOMIC_RELAXED, __HIP_MEMORY_SCOPE_AGENT);
        } else if (tid < 192) {
            const int rr = tid - 96;
            const int j = (rr >> 5)*128 + q*32 + (rr & 31);
            float a = sh_bhh[rr] + sh_hhp[rr*2] + sh_hhp[rr*2 + 1];
            __hip_atomic_store(&exch_ihhh[384 + j], a, __ATOMIC_RELAXED, __HIP_MEMORY_SCOPE_AGENT);
        }
        asm volatile("s_waitcnt vmcnt(0)" ::: "memory");
        __syncthreads();
        if (tid == 0)
            __hip_atomic_fetch_add(flagA, 1, __ATOMIC_RELAXED, __HIP_MEMORY_SCOPE_AGENT);

        // ===== S3: whh (long phase, hides sync1); wave15: poll + preload =====
        if (tid < 768) {
            const int half = (tid >= 384);
            const int rr = half ? (tid - 384) : tid;
            const uint4* W0 = WHq + (half ? 32*384 : 0) + rr;
            const float4* hblk = h4 + half*64;
            float a0 = 0.f;
            #pragma unroll 8
            for (int k8 = 0; k8 < 32; ++k8)
                a0 += dotbf8(W0[k8*384], hblk[2*k8], hblk[2*k8 + 1]);
            sh_whhp[half*384 + rr] = a0;
        } else if (tid >= 960) {
            if (lane == 0) {
                while (__hip_atomic_load(flagA, __ATOMIC_RELAXED, __HIP_MEMORY_SCOPE_AGENT) < 4*(t+1))
                    __builtin_amdgcn_s_sleep(1);
            }
            #pragma unroll
            for (int jj = 0; jj < 12; ++jj)
                sh_ihhh[lane + 64*jj] = __hip_atomic_load(&exch_ihhh[lane + 64*jj],
                                            __ATOMIC_RELAXED, __HIP_MEMORY_SCOPE_AGENT);
        }
        __syncthreads();

        // ===== S4: hyper-GRU elementwise + x_{t+1} prefetch =====
        if (tid < 128) {
            const int j = tid;
            float rg = sigmoidf_(sh_ihhh[j]       + sh_ihhh[384 + j]);
            float gg = sigmoidf_(sh_ihhh[128 + j] + sh_ihhh[512 + j]);
            float nn = tanhf_(sh_ihhh[256 + j] + rg * sh_ihhh[640 + j]);
            float hn = nn + gg * (sh_hat[j] - nn);
            sh_hat[j] = hn;
            if (t == TT - 1 && q == 0)
                __builtin_nontemporal_store(hn,
                    &out[(size_t)BB*TT*HH + (size_t)BB*HH + (size_t)b*ZHH + j]);
        } else if (tid >= 128 && tid < 192 && t + 1 < TT) {
            sh_x[tid - 128] = xs[((size_t)b*TT + t + 1)*IN + (tid - 128)];
        }
        __syncthreads();

        // ===== S5: z = hhat_new @ zw.T (288 rows, K=128) =====
        if (tid < 288) {
            float acc = sh_bz[tid];
            const float4* nhat4 = (const float4*)sh_hat;
            if (HZP) {
                const uint4* W = ZWB + tid;
                #pragma unroll 8
                for (int k8 = 0; k8 < 16; ++k8)
                    acc += dotbf8(W[k8*288], nhat4[2*k8], nhat4[2*k8 + 1]);
            } else {
                const float* src = (tid < 96) ? (zh_w + (size_t)tid*128)
                                 : ((tid < 192) ? (zx_w + (size_t)(tid - 96)*128)
                                                : (zb_w + (size_t)(tid - 192)*128));
                const float4* W = (const float4*)src;
                #pragma unroll 8
                for (int k4 = 0; k4 < 32; ++k4) acc += dot4_(W[k4], nhat4[k4]);
            }
            sh_z[tid] = acc;
        }
        __syncthreads();

        // ===== S6: d quarter (1152 rows, K=32, bf16) =====
        #pragma unroll
        for (int rp = 0; rp < 2; ++rp) {
            const int rr = tid + rp*NT;
            if (rr < 1152) {
                const int u9 = rr >> 7;
                const int kind = u9 / 3, l = u9 - kind*3;
                const uint4* W = DWq + rr;
                const float4* Z = (const float4*)(&sh_z[kind*96 + l*32]);
                float acc = 0.f;
                #pragma unroll
                for (int k8 = 0; k8 < 4; ++k8)
                    acc += dotbf8(W[k8*1152], Z[2*k8], Z[2*k8 + 1]);
                sh_d[rr] = acc;
            }
        }
        __syncthreads();

        // ===== S7: gates -> h_new quarter, publish =====
        if (tid < 128) {
            const int hl = tid, hg = q*128 + hl;
            float whh0 = sh_whhp[hl]       + sh_whhp[384 + hl];
            float whh1 = sh_whhp[128 + hl] + sh_whhp[512 + hl];
            float whh2 = sh_whhp[256 + hl] + sh_whhp[640 + hl];
            float wxx0 = sh_wxx[hl], wxx1 = sh_wxx[128 + hl], wxx2 = sh_wxx[256 + hl];
            float dh0 = sh_d[hl],       dh1 = sh_d[128 + hl], dh2 = sh_d[256 + hl];
            float dx0 = sh_d[384 + hl], dx1 = sh_d[512 + hl], dx2 = sh_d[640 + hl];
            float db0 = sh_d[768 + hl]  + sh_bdb[hl];
            float db1 = sh_d[896 + hl]  + sh_bdb[128 + hl];
            float db2 = sh_d[1024 + hl] + sh_bdb[256 + hl];
            float r0 = sigmoidf_(dh0*whh0 + dx0*wxx0 + db0);
            float g0 = sigmoidf_(dh1*whh1 + dx1*wxx1 + db1);
            float n0 = tanhf_(r0*dh2*whh2 + dx2*wxx2 + db2);
            float hold = sh_h[hg];
            float hnew = n0 + g0*(hold - n0);
            __builtin_nontemporal_store(hnew, &out[((size_t)b*TT + t)*HH + hg]);
            if (t == TT - 1)
                __builtin_nontemporal_store(hnew, &out[(size_t)BB*TT*HH + (size_t)b*512 + hg]);
            __hip_atomic_store(&exch_h[hg], hnew, __ATOMIC_RELAXED, __HIP_MEMORY_SCOPE_AGENT);
        }
        asm volatile("s_waitcnt vmcnt(0)" ::: "memory");
        __syncthreads();
        if (tid == 0)
            __hip_atomic_fetch_add(flagB, 1, __ATOMIC_RELAXED, __HIP_MEMORY_SCOPE_AGENT);

        // ===== S8: wxx(t+1) while wave15 polls + preloads h =====
        if (tid < 384) {
            if (t + 1 < TT) {
                float a1 = 0.f;
                const uint4* X0 = WXq + tid;
                const float4* x4 = (const float4*)sh_x;
                #pragma unroll
                for (int k8 = 0; k8 < 8; ++k8)
                    a1 += dotbf8(X0[k8*384], x4[2*k8], x4[2*k8 + 1]);
                sh_wxx[tid] = a1;
            }
        } else if (tid >= 960) {
            if (lane == 0) {
                while (__hip_atomic_load(flagB, __ATOMIC_RELAXED, __HIP_MEMORY_SCOPE_AGENT) < 4*(t+1))
                    __builtin_amdgcn_s_sleep(1);
            }
            #pragma unroll
            for (int jj = 0; jj < 8; ++jj)
                sh_h[lane + 64*jj] = __hip_atomic_load(&exch_h[lane + 64*jj],
                                         __ATOMIC_RELAXED, __HIP_MEMORY_SCOPE_AGENT);
        }
        __syncthreads();
    }
}

// ---------- fp32 fallback (proven; used only if ws too small) ----------
__device__ __forceinline__ float wred(float v) {
    v += __shfl_xor(v, 32, 64); v += __shfl_xor(v, 16, 64); v += __shfl_xor(v, 8, 64);
    v += __shfl_xor(v, 4, 64);  v += __shfl_xor(v, 2, 64);  v += __shfl_xor(v, 1, 64);
    return v;
}
__global__ __launch_bounds__(1024)
void hypercell_batch(
    const float* __restrict__ xs, const float* __restrict__ cond,
    const float* __restrict__ h_c, const float* __restrict__ h_c_hat,
    const float* __restrict__ x2h_w, const float* __restrict__ x2h_b,
    const float* __restrict__ h2h_w, const float* __restrict__ h2h_b,
    const float* __restrict__ zh_w, const float* __restrict__ zh_b,
    const float* __restrict__ zx_w, const float* __restrict__ zx_b,
    const float* __restrict__ zb_w,
    const float* __restrict__ dh_w, const float* __restrict__ dx_w,
    const float* __restrict__ db_w, const float* __restrict__ db_b,
    const float* __restrict__ wh, const float* __restrict__ wx,
    float* __restrict__ out)
{
    __shared__ float h_s[HH];
    __shared__ float hhat_s[ZHH];
    __shared__ float x_s[IN];
    __shared__ float cond_s[IN];
    __shared__ float whh_s[3*HH];
    __shared__ float wxx_s[3*HH];
    __shared__ float ih_s[3*ZHH];
    __shared__ float hh_s[3*ZHH];
    __shared__ float z_s[288];
    const int b = blockIdx.x, tid = threadIdx.x, lane = tid & 63, wv = tid >> 6;
    if (tid < IN)  cond_s[tid] = cond[(size_t)b*IN + tid];
    if (tid < HH)  h_s[tid]    = h_c[(size_t)b*HH + tid];
    if (tid < ZHH) hhat_s[tid] = h_c_hat[(size_t)b*ZHH + tid];
    __syncthreads();
    for (int t = 0; t < TT; ++t) {
        if (tid < IN) x_s[tid] = xs[((size_t)b*TT + t)*IN + tid];
        const float4* h4 = (const float4*)h_s;
        const float4 ha = h4[lane]; const float4 hb = h4[64 + lane];
        {
            const float* wl = wh + (size_t)(wv*96)*HH + lane*4;
            #pragma unroll 4
            for (int i = 0; i < 96; ++i) {
                float p = wred(dot4_(*(const float4*)(wl + (size_t)i*HH), ha)
                             + dot4_(*(const float4*)(wl + (size_t)i*HH + 256), hb));
                if (lane == 0) whh_s[wv*96 + i] = p;
            }
        }
        {
            const float cv = cond_s[lane];
            const float* wbase = x2h_w + (size_t)(wv*24)*576;
            #pragma unroll 2
            for (int i = 0; i < 24; ++i) {
                const float* wr = wbase + (size_t)i*576;
                float p = wred(dot4_(*(const float4*)(wr + lane*4), ha)
                             + dot4_(*(const float4*)(wr + 256 + lane*4), hb) + wr[512 + lane]*cv);
                if (lane == 0) ih_s[wv*24 + i] = p + x2h_b[wv*24 + i];
            }
        }
        {
            const float2 hv = ((const float2*)hhat_s)[lane];
            const float* wbase = h2h_w + (size_t)(wv*24)*ZHH;
            #pragma unroll 4
            for (int i = 0; i < 24; ++i) {
                float2 wq = *(const float2*)(wbase + (size_t)i*ZHH + lane*2);
                float p = wred(wq.x*hv.x + wq.y*hv.y);
                if (lane == 0) hh_s[wv*24 + i] = p + h2h_b[wv*24 + i];
            }
        }
        __syncthreads();
        {
            const float4* x4 = (const float4*)x_s;
            {
                const float4* wr = (const float4*)(wx + (size_t)tid*IN);
                float acc = 0.f;
                #pragma unroll
                for (int j = 0; j < 16; ++j) acc += dot4_(wr[j], x4[j]);
                wxx_s[tid] = acc;
            }
            if (tid < 512) {
                const int r = 1024 + tid;
                const float4* wr = (const float4*)(wx + (size_t)r*IN);
                float acc = 0.f;
                #pragma unroll
                for (int j = 0; j < 16; ++j) acc += dot4_(wr[j], x4[j]);
                wxx_s[r] = acc;
            }
        }
        if (tid < ZHH) {
            const int j = tid;
            float r = sigmoidf_(ih_s[j] + hh_s[j]);
            float g = sigmoidf_(ih_s[ZHH+j] + hh_s[ZHH+j]);
            float n = tanhf(ih_s[2*ZHH+j] + r*hh_s[2*ZHH+j]);
            float hn = n + g*(hhat_s[j] - n);
            hhat_s[j] = hn;
            if (t == TT-1)
                out[(size_t)BB*TT*HH + (size_t)BB*HH + (size_t)b*ZHH + j] = hn;
        }
        __syncthreads();
        {
            const float2 hv = ((const float2*)hhat_s)[lane];
            #pragma unroll 2
            for (int i = 0; i < 18; ++i) {
                const int R = wv*18 + i, kind = R / 96, r96 = R % 96;
                const float* wsrc = (kind == 0) ? zh_w : ((kind == 1) ? zx_w : zb_w);
                float2 wq = *(const float2*)(wsrc + (size_t)r96*ZHH + lane*2);
                float p = wred(wq.x*hv.x + wq.y*hv.y);
                if (lane == 0)
                    z_s[R] = p + ((kind == 0) ? zh_b[r96] : ((kind == 1) ? zx_b[r96] : 0.f));
            }
        }
        __syncthreads();
        if (tid < HH) {
            const int h = tid;
            const float* dsrc[3] = { dh_w, dx_w, db_w };
            float dv[3][3];
            #pragma unroll
            for (int kind = 0; kind < 3; ++kind)
                #pragma unroll
                for (int l = 0; l < 3; ++l) {
                    const float4* wr = (const float4*)(dsrc[kind] + ((size_t)l*HH + h)*32);
                    const float4* zp = (const float4*)&z_s[kind*96 + l*32];
                    float acc = 0.f;
                    #pragma unroll
                    for (int j = 0; j < 8; ++j) acc += dot4_(wr[j], zp[j]);
                    dv[kind][l] = acc;
                }
            float whh0 = whh_s[h], whh1 = whh_s[HH+h], whh2 = whh_s[2*HH+h];
            float wxx0 = wxx_s[h], wxx1 = wxx_s[HH+h], wxx2 = wxx_s[2*HH+h];
            float db0 = dv[2][0] + db_b[h], db1 = dv[2][1] + db_b[HH+h], db2 = dv[2][2] + db_b[2*HH+h];
            float r0 = sigmoidf_(dv[0][0]*whh0 + dv[1][0]*wxx0 + db0);
            float g0 = sigmoidf_(dv[0][1]*whh1 + dv[1][1]*wxx1 + db1);
            float n0 = tanhf(r0*dv[0][2]*whh2 + dv[1][2]*wxx2 + db2);
            float hold = h_s[h];
            float hnew = n0 + g0*(hold - n0);
            h_s[h] = hnew;
            out[((size_t)b*TT + t)*HH + h] = hnew;
            if (t == TT-1) out[(size_t)BB*TT*HH + (size_t)b*HH + h] = hnew;
        }
        __syncthreads();
    }
}

extern "C" void kernel_launch(void* const* d_in, const int* in_sizes, int n_in,
                              void* d_out, int out_size, void* d_ws, size_t ws_size,
                              hipStream_t stream) {
    const float* xs      = (const float*)d_in[0];
    const float* cond    = (const float*)d_in[1];
    const float* h_c     = (const float*)d_in[2];
    const float* h_c_hat = (const float*)d_in[3];
    const float* x2h_w   = (const float*)d_in[4];
    const float* x2h_b   = (const float*)d_in[5];
    const float* h2h_w   = (const float*)d_in[6];
    const float* h2h_b   = (const float*)d_in[7];
    const float* zh_w    = (const float*)d_in[8];
    const float* zh_b    = (const float*)d_in[9];
    const float* zx_w    = (const float*)d_in[10];
    const float* zx_b    = (const float*)d_in[11];
    const float* zb_w    = (const float*)d_in[12];
    const float* dh_w    = (const float*)d_in[13];
    const float* dx_w    = (const float*)d_in[14];
    const float* db_w    = (const float*)d_in[15];
    const float* db_b    = (const float*)d_in[16];
    const float* wh      = (const float*)d_in[17];
    const float* wx      = (const float*)d_in[18];
    float* out = (float*)d_out;

    if (ws_size >= (size_t)WS_NOX2H) {
        char* wsb = (char*)d_ws;
        const int full = (ws_size >= (size_t)WS_FULL) ? 1 : 0;
        const int xtra = (ws_size >= (size_t)WS_XTRA) ? 1 : 0;
        hipMemsetAsync(wsb + OFF_FLAG, 0, 8192, stream);
        hipLaunchKernelGGL(pack_w, dim3(654), dim3(256), 0, stream,
                           wh, wx, dh_w, dx_w, db_w, x2h_w, h2h_w,
                           zh_w, zx_w, zb_w, full, xtra, wsb);
        if (xtra) {
            hipLaunchKernelGGL((hypercell_q<1,1>), dim3(256), dim3(NT), 0, stream,
                               xs, cond, h_c, h_c_hat, x2h_w, x2h_b, h2h_w, h2h_b,
                               zh_w, zh_b, zx_w, zx_b, zb_w, db_b, wsb, out);
        } else if (full) {
            hipLaunchKernelGGL((hypercell_q<1,0>), dim3(256), dim3(NT), 0, stream,
                               xs, cond, h_c, h_c_hat, x2h_w, x2h_b, h2h_w, h2h_b,
                               zh_w, zh_b, zx_w, zx_b, zb_w, db_b, wsb, out);
        } else {
            hipLaunchKernelGGL((hypercell_q<0,0>), dim3(256), dim3(NT), 0, stream,
                               xs, cond, h_c, h_c_hat, x2h_w, x2h_b, h2h_w, h2h_b,
                               zh_w, zh_b, zx_w, zx_b, zb_w, db_b, wsb, out);
        }
    } else {
        hipLaunchKernelGGL(hypercell_batch, dim3(BB), dim3(1024), 0, stream,
                           xs, cond, h_c, h_c_hat, x2h_w, x2h_b, h2h_w, h2h_b,
                           zh_w, zh_b, zx_w, zx_b, zb_w, dh_w, dx_w, db_w, db_b,
                           wh, wx, out);
    }
}

// Round 9
// 15854.755 us; speedup vs baseline: 1.1219x; 1.1219x over previous
//
#include <hip/hip_runtime.h>
#include <math.h>

// Problem constants
#define BB  64
#define TT  512
#define IN  64
#define HH  512
#define ZHH 128
#define NT  1024
#define NS  8          // slices per batch

// ---- ws layout (byte offsets); optional regions at the tail ----
#define OFF_EXIH   0u          // f32 [64][768]
#define OFF_EXH    196608u     // f32 [64][512]
#define OFF_FLAG   327680u     // 2*64 ints, 64B stride
#define OFF_WH     335872u     // bf16 [s<8][k8<64][192][8]
#define OFF_WX     1908736u    // bf16 [s<8][k8<8][192][8]
#define OFF_DW     2105344u    // bf16 [s<8][k8<4][576][8]
#define OFF_X2H    2400256u    // bf16 [s<8][k8<72][48][8]
#define OFF_H2HB   2842624u    // bf16 [s<8][k8<16][48][8]
#define OFF_ZWB    2940928u    // bf16 [k8<16][288][8]
#define WS_NOX2H   2400256u
#define WS_FULL    2842624u
#define WS_XTRA    3014656u

__device__ __forceinline__ float sigmoidf_(float x) {
    return 1.0f / (1.0f + __expf(-x));
}
__device__ __forceinline__ float tanhf_(float x) {
    return 2.0f / (1.0f + __expf(-2.0f * x)) - 1.0f;
}
__device__ __forceinline__ float bflo(unsigned u) { return __uint_as_float(u << 16); }
__device__ __forceinline__ float bfhi(unsigned u) { return __uint_as_float(u & 0xffff0000u); }
__device__ __forceinline__ unsigned short f2bf(float f) {
    unsigned u = __float_as_uint(f);
    return (unsigned short)((u + 0x7fffu + ((u >> 16) & 1u)) >> 16);
}
__device__ __forceinline__ float dotbf8(uint4 U, float4 a, float4 b) {
    return bflo(U.x)*a.x + bfhi(U.x)*a.y + bflo(U.y)*a.z + bfhi(U.y)*a.w
         + bflo(U.z)*b.x + bfhi(U.z)*b.y + bflo(U.w)*b.z + bfhi(U.w)*b.w;
}
__device__ __forceinline__ float dot4_(const float4 a, const float4 b) {
    return a.x*b.x + a.y*b.y + a.z*b.z + a.w*b.w;
}
__device__ __forceinline__ uint4 packbf8(const float* s) {
    float4 a = *(const float4*)s;
    float4 c = *(const float4*)(s + 4);
    uint4 q;
    q.x = (unsigned)f2bf(a.x) | ((unsigned)f2bf(a.y) << 16);
    q.y = (unsigned)f2bf(a.z) | ((unsigned)f2bf(a.w) << 16);
    q.z = (unsigned)f2bf(c.x) | ((unsigned)f2bf(c.y) << 16);
    q.w = (unsigned)f2bf(c.z) | ((unsigned)f2bf(c.w) << 16);
    return q;
}

// ---------- pre-pass: eighth-sliced bf16 repack ----------
__global__ __launch_bounds__(256)
void pack_w(const float* __restrict__ wh, const float* __restrict__ wx,
            const float* __restrict__ dh_w, const float* __restrict__ dx_w,
            const float* __restrict__ db_w, const float* __restrict__ x2h_w,
            const float* __restrict__ h2h_w, const float* __restrict__ zh_w,
            const float* __restrict__ zx_w, const float* __restrict__ zb_w,
            int packX2H, int packHZ, char* __restrict__ wsb)
{
    const int u = blockIdx.x * 256 + threadIdx.x;
    if (u < 98304) {                                   // WH: 8*64*192
        int s = u / 12288, r1 = u % 12288, k8 = r1 / 192, rr = r1 % 192;
        int g = rr >> 6, hl = rr & 63, h = s*64 + hl;
        ((uint4*)(wsb + OFF_WH))[u] = packbf8(wh + ((size_t)(g*512 + h))*512 + k8*8);
    } else if (u < 110592) {                           // WX: 8*8*192
        int v = u - 98304;
        int s = v / 1536, r1 = v % 1536, k8 = r1 / 192, rr = r1 % 192;
        int g = rr >> 6, hl = rr & 63, h = s*64 + hl;
        ((uint4*)(wsb + OFF_WX))[v] = packbf8(wx + ((size_t)(g*512 + h))*64 + k8*8);
    } else if (u < 129024) {                           // DW: 8*4*576
        int v = u - 110592;
        int s = v / 2304, r1 = v % 2304, k8 = r1 / 576, rr = r1 % 576;
        int u9 = rr >> 6, hl = rr & 63, h = s*64 + hl;
        int kind = u9 / 3, l = u9 - kind*3;
        const float* dsrc = (kind == 0) ? dh_w : ((kind == 1) ? dx_w : db_w);
        ((uint4*)(wsb + OFF_DW))[v] = packbf8(dsrc + ((size_t)(l*512) + h)*32 + k8*8);
    } else if (u < 156672) {                           // X2H: 8*72*48
        if (!packX2H) return;
        int v = u - 129024;
        int s = v / 3456, r1 = v % 3456, k8 = r1 / 48, rr = r1 % 48;
        int g = rr >> 4, zz = rr & 15, j = g*128 + s*16 + zz;
        ((uint4*)(wsb + OFF_X2H))[v] = packbf8(x2h_w + (size_t)j*576 + k8*8);
    } else if (u < 162816) {                           // H2HB: 8*16*48
        if (!packHZ) return;
        int v = u - 156672;
        int s = v / 768, r1 = v % 768, k8 = r1 / 48, rr = r1 % 48;
        int g = rr >> 4, zz = rr & 15, j = g*128 + s*16 + zz;
        ((uint4*)(wsb + OFF_H2HB))[v] = packbf8(h2h_w + (size_t)j*128 + k8*8);
    } else if (u < 167424) {                           // ZWB: 16*288
        if (!packHZ) return;
        int v = u - 162816;
        int k8 = v / 288, r = v % 288;
        const float* src = (r < 96) ? (zh_w + (size_t)r*128)
                         : ((r < 192) ? (zx_w + (size_t)(r - 96)*128)
                                      : (zb_w + (size_t)(r - 192)*128));
        ((uint4*)(wsb + OFF_ZWB))[v] = packbf8(src + k8*8);
    }
}

// ---------- main: 512 WGs = 64 batches x 8 slices -> 2 WGs/CU ----------
// __launch_bounds__(1024, 8): 8 waves/EU -> 2 blocks/CU -> VGPR hard-capped at 64.
// REQUIRED for correctness: the per-batch flag sync needs all 8 sibling WGs
// co-resident; at >64 VGPRs only 1 WG/CU fits and the kernel deadlocks
// (R8 failure hypothesis). R5's kernel compiled to exactly 64 VGPRs, so the
// cap should be achievable without heavy spilling.
template<int X2HP, int HZP>
__global__ __launch_bounds__(NT, 8)
void hypercell_s(
    const float* __restrict__ xs, const float* __restrict__ cond,
    const float* __restrict__ h_c, const float* __restrict__ h_c_hat,
    const float* __restrict__ x2h_w, const float* __restrict__ x2h_b,
    const float* __restrict__ h2h_w, const float* __restrict__ h2h_b,
    const float* __restrict__ zh_w, const float* __restrict__ zh_b,
    const float* __restrict__ zx_w, const float* __restrict__ zx_b,
    const float* __restrict__ zb_w, const float* __restrict__ db_b,
    char* __restrict__ wsb, float* __restrict__ out)
{
    __shared__ __align__(16) float sh_h[512];
    __shared__ __align__(16) float sh_hat[128];
    __shared__ __align__(16) float sh_x[2][64];   // double-buffered x
    __shared__ __align__(16) float sh_c[64];
    __shared__ __align__(16) float sh_z[288];
    __shared__ float sh_whhp[768];   // [kq<4][192]
    __shared__ float sh_wxx[192];
    __shared__ float sh_ihp[192];    // [p<4][48]
    __shared__ float sh_hhv[48];
    __shared__ float sh_d[576];
    __shared__ float sh_bih[48];
    __shared__ float sh_bhh[48];
    __shared__ float sh_bz[288];
    __shared__ float sh_bdb[192];

    const int b   = blockIdx.x & 63;     // batch
    const int s   = blockIdx.x >> 6;     // slice (siblings same XCD)
    const int tid = threadIdx.x;

    const uint4* WHs   = (const uint4*)(wsb + OFF_WH)   + s*12288;
    const uint4* WXs   = (const uint4*)(wsb + OFF_WX)   + s*1536;
    const uint4* DWs   = (const uint4*)(wsb + OFF_DW)   + s*2304;
    const uint4* X2Hs  = (const uint4*)(wsb + OFF_X2H)  + s*3456;
    const uint4* H2HBs = (const uint4*)(wsb + OFF_H2HB) + s*768;
    const uint4* ZWB   = (const uint4*)(wsb + OFF_ZWB);

    float* exch_ihhh = (float*)(wsb + OFF_EXIH) + (size_t)b*768;
    float* exch_h    = (float*)(wsb + OFF_EXH)  + (size_t)b*512;
    int* flagA = (int*)(wsb + OFF_FLAG + (size_t)b*64);
    int* flagB = (int*)(wsb + OFF_FLAG + 4096 + (size_t)b*64);

    // ---- init staging ----
    if (tid < 48) {
        int j = (tid >> 4)*128 + s*16 + (tid & 15);
        sh_bih[tid] = x2h_b[j];
        sh_bhh[tid] = h2h_b[j];
    }
    if (tid < 288) sh_bz[tid] = (tid < 96) ? zh_b[tid]
                              : ((tid < 192) ? zx_b[tid - 96] : 0.f);
    if (tid < 192) {
        int l = tid >> 6, hl = tid & 63;
        sh_bdb[tid] = db_b[l*512 + s*64 + hl];
    }
    if (tid < 512) sh_h[tid] = h_c[(size_t)b*512 + tid];
    if (tid < 128) sh_hat[tid] = h_c_hat[(size_t)b*128 + tid];
    if (tid < 64) {
        sh_c[tid] = cond[(size_t)b*64 + tid];
        sh_x[0][tid] = xs[(size_t)b*TT*IN + tid];
    }
    __syncthreads();

    for (int t = 0; t < TT; ++t) {
        const float4* h4   = (const float4*)sh_h;
        const float4* hat4 = (const float4*)sh_hat;
        const float4* c4   = (const float4*)sh_c;

        // ===== Phase A: all recurrent matvecs on old state (R5 order) =====
        if (tid < 768) {
            // whh: 192 rows x 4 K-quarters (K=128 each), bf16
            const int kq = tid / 192;
            const int rr = tid - kq*192;
            const uint4* W0 = WHs + kq*(16*192) + rr;
            const float4* hblk = h4 + kq*32;
            float a0 = 0.f;
            #pragma unroll 8
            for (int k8 = 0; k8 < 16; ++k8)
                a0 += dotbf8(W0[k8*192], hblk[2*k8], hblk[2*k8 + 1]);
            sh_whhp[kq*192 + rr] = a0;
        } else if (tid < 960) {
            // ih: 48 rows x 4 K-parts (k8: [0,18)[18,36)[36,54)[54,72))
            const int u = tid - 768;
            const int p = u / 48;
            const int rr = u - p*48;
            float a = 0.f;
            if (X2HP) {
                const uint4* W0 = X2Hs + rr;
                if (p < 3) {
                    #pragma unroll
                    for (int k8 = 18*p; k8 < 18*p + 18; ++k8)
                        a += dotbf8(W0[k8*48], h4[2*k8], h4[2*k8 + 1]);
                } else {
                    #pragma unroll
                    for (int k8 = 54; k8 < 64; ++k8)
                        a += dotbf8(W0[k8*48], h4[2*k8], h4[2*k8 + 1]);
                    #pragma unroll
                    for (int k8 = 64; k8 < 72; ++k8)
                        a += dotbf8(W0[k8*48], c4[2*(k8-64)], c4[2*(k8-64) + 1]);
                }
            } else {
                const int j = (rr >> 4)*128 + s*16 + (rr & 15);
                const float4* wr = (const float4*)(x2h_w + (size_t)j*576);
                if (p < 3) {
                    #pragma unroll
                    for (int k4 = 36*p; k4 < 36*p + 36; ++k4)
                        a += dot4_(wr[k4], h4[k4]);
                } else {
                    #pragma unroll
                    for (int k4 = 108; k4 < 128; ++k4) a += dot4_(wr[k4], h4[k4]);
                    #pragma unroll
                    for (int k4 = 128; k4 < 144; ++k4) a += dot4_(wr[k4], c4[k4 - 128]);
                }
            }
            sh_ihp[p*48 + rr] = a;
        } else if (tid < 1008) {
            // hh: 48 rows full K=128
            const int rr = tid - 960;
            float a = sh_bhh[rr];
            if (HZP) {
                const uint4* W = H2HBs + rr;
                #pragma unroll 8
                for (int k8 = 0; k8 < 16; ++k8)
                    a += dotbf8(W[k8*48], hat4[2*k8], hat4[2*k8 + 1]);
            } else {
                const int j = (rr >> 4)*128 + s*16 + (rr & 15);
                const float4* wr = (const float4*)(h2h_w + (size_t)j*128);
                #pragma unroll 8
                for (int k4 = 0; k4 < 32; ++k4) a += dot4_(wr[k4], hat4[k4]);
            }
            sh_hhv[rr] = a;
        }
        __syncthreads();

        // ===== publish ih/hh (sync1, count to 8) =====
        if (tid < 48) {
            const int j = (tid >> 4)*128 + s*16 + (tid & 15);
            float a = sh_bih[tid] + sh_ihp[tid] + sh_ihp[48 + tid]
                    + sh_ihp[96 + tid] + sh_ihp[144 + tid];
            __hip_atomic_store(&exch_ihhh[j], a, __ATOMIC_RELAXED, __HIP_MEMORY_SCOPE_AGENT);
        } else if (tid < 96) {
            const int rr = tid - 48;
            const int j = (rr >> 4)*128 + s*16 + (rr & 15);
            __hip_atomic_store(&exch_ihhh[384 + j], sh_hhv[rr],
                               __ATOMIC_RELAXED, __HIP_MEMORY_SCOPE_AGENT);
        }
        asm volatile("s_waitcnt vmcnt(0)" ::: "memory");
        __syncthreads();
        if (tid == 0) {
            __hip_atomic_fetch_add(flagA, 1, __ATOMIC_RELAXED, __HIP_MEMORY_SCOPE_AGENT);
            while (__hip_atomic_load(flagA, __ATOMIC_RELAXED, __HIP_MEMORY_SCOPE_AGENT) < NS*(t+1))
                __builtin_amdgcn_s_sleep(1);
        }
        __syncthreads();

        // ===== Phase B: hyper-GRU elementwise (reads exch direct) + x prefetch =====
        if (tid < 128) {
            const int j = tid;
            float i_r = __hip_atomic_load(&exch_ihhh[j],       __ATOMIC_RELAXED, __HIP_MEMORY_SCOPE_AGENT);
            float i_i = __hip_atomic_load(&exch_ihhh[128 + j], __ATOMIC_RELAXED, __HIP_MEMORY_SCOPE_AGENT);
            float i_n = __hip_atomic_load(&exch_ihhh[256 + j], __ATOMIC_RELAXED, __HIP_MEMORY_SCOPE_AGENT);
            float h_r = __hip_atomic_load(&exch_ihhh[384 + j], __ATOMIC_RELAXED, __HIP_MEMORY_SCOPE_AGENT);
            float h_i = __hip_atomic_load(&exch_ihhh[512 + j], __ATOMIC_RELAXED, __HIP_MEMORY_SCOPE_AGENT);
            float h_n = __hip_atomic_load(&exch_ihhh[640 + j], __ATOMIC_RELAXED, __HIP_MEMORY_SCOPE_AGENT);
            float rg = sigmoidf_(i_r + h_r);
            float gg = sigmoidf_(i_i + h_i);
            float nn = tanhf_(i_n + rg * h_n);
            float hn = nn + gg * (sh_hat[j] - nn);
            sh_hat[j] = hn;
            if (t == TT - 1 && s == 0)
                __builtin_nontemporal_store(hn,
                    &out[(size_t)BB*TT*HH + (size_t)BB*HH + (size_t)b*ZHH + j]);
        } else if (tid >= 128 && tid < 192 && t + 1 < TT) {
            sh_x[(t + 1) & 1][tid - 128] = xs[((size_t)b*TT + t + 1)*IN + (tid - 128)];
        }
        __syncthreads();

        // ===== z = hhat_new @ zw.T (288 rows, K=128, redundant) =====
        if (tid < 288) {
            float acc = sh_bz[tid];
            const float4* nhat4 = (const float4*)sh_hat;
            if (HZP) {
                const uint4* W = ZWB + tid;
                #pragma unroll 8
                for (int k8 = 0; k8 < 16; ++k8)
                    acc += dotbf8(W[k8*288], nhat4[2*k8], nhat4[2*k8 + 1]);
            } else {
                const float* src = (tid < 96) ? (zh_w + (size_t)tid*128)
                                 : ((tid < 192) ? (zx_w + (size_t)(tid - 96)*128)
                                                : (zb_w + (size_t)(tid - 192)*128));
                const float4* W = (const float4*)src;
                #pragma unroll 8
                for (int k4 = 0; k4 < 32; ++k4) acc += dot4_(W[k4], nhat4[k4]);
            }
            sh_z[tid] = acc;
        }
        __syncthreads();

        // ===== d slice (576 rows, K=32) + wxx (192 rows, K=64) =====
        if (tid < 576) {
            const int u9 = tid >> 6;
            const int kind = u9 / 3, l = u9 - kind*3;
            const uint4* W = DWs + tid;
            const float4* Z = (const float4*)(&sh_z[kind*96 + l*32]);
            float acc = 0.f;
            #pragma unroll
            for (int k8 = 0; k8 < 4; ++k8)
                acc += dotbf8(W[k8*576], Z[2*k8], Z[2*k8 + 1]);
            sh_d[tid] = acc;
        } else if (tid < 768) {
            const int rr = tid - 576;
            const uint4* X0 = WXs + rr;
            const float4* xc4 = (const float4*)sh_x[t & 1];
            float a1 = 0.f;
            #pragma unroll
            for (int k8 = 0; k8 < 8; ++k8)
                a1 += dotbf8(X0[k8*192], xc4[2*k8], xc4[2*k8 + 1]);
            sh_wxx[rr] = a1;
        }
        __syncthreads();

        // ===== gates -> h_new slice (64 rows), publish (sync2) =====
        if (tid < 64) {
            const int hl = tid, hg = s*64 + hl;
            float whh0 = sh_whhp[hl]        + sh_whhp[192 + hl]
                       + sh_whhp[384 + hl]  + sh_whhp[576 + hl];
            float whh1 = sh_whhp[64 + hl]   + sh_whhp[256 + hl]
                       + sh_whhp[448 + hl]  + sh_whhp[640 + hl];
            float whh2 = sh_whhp[128 + hl]  + sh_whhp[320 + hl]
                       + sh_whhp[512 + hl]  + sh_whhp[704 + hl];
            float wxx0 = sh_wxx[hl], wxx1 = sh_wxx[64 + hl], wxx2 = sh_wxx[128 + hl];
            float dh0 = sh_d[hl],        dh1 = sh_d[64 + hl],  dh2 = sh_d[128 + hl];
            float dx0 = sh_d[192 + hl],  dx1 = sh_d[256 + hl], dx2 = sh_d[320 + hl];
            float db0 = sh_d[384 + hl] + sh_bdb[hl];
            float db1 = sh_d[448 + hl] + sh_bdb[64 + hl];
            float db2 = sh_d[512 + hl] + sh_bdb[128 + hl];
            float r0 = sigmoidf_(dh0*whh0 + dx0*wxx0 + db0);
            float g0 = sigmoidf_(dh1*whh1 + dx1*wxx1 + db1);
            float n0 = tanhf_(r0*dh2*whh2 + dx2*wxx2 + db2);
            float hold = sh_h[hg];
            float hnew = n0 + g0*(hold - n0);
            __builtin_nontemporal_store(hnew, &out[((size_t)b*TT + t)*HH + hg]);
            if (t == TT - 1)
                __builtin_nontemporal_store(hnew, &out[(size_t)BB*TT*HH + (size_t)b*512 + hg]);
            __hip_atomic_store(&exch_h[hg], hnew, __ATOMIC_RELAXED, __HIP_MEMORY_SCOPE_AGENT);
        }
        asm volatile("s_waitcnt vmcnt(0)" ::: "memory");
        __syncthreads();
        if (tid == 0) {
            __hip_atomic_fetch_add(flagB, 1, __ATOMIC_RELAXED, __HIP_MEMORY_SCOPE_AGENT);
            while (__hip_atomic_load(flagB, __ATOMIC_RELAXED, __HIP_MEMORY_SCOPE_AGENT) < NS*(t+1))
                __builtin_amdgcn_s_sleep(1);
        }
        __syncthreads();
        if (tid < 512)
            sh_h[tid] = __hip_atomic_load(&exch_h[tid], __ATOMIC_RELAXED, __HIP_MEMORY_SCOPE_AGENT);
        __syncthreads();
    }
}

// ---------- fp32 fallback (proven; used only if ws too small) ----------
__device__ __forceinline__ float wred(float v) {
    v += __shfl_xor(v, 32, 64); v += __shfl_xor(v, 16, 64); v += __shfl_xor(v, 8, 64);
    v += __shfl_xor(v, 4, 64);  v += __shfl_xor(v, 2, 64);  v += __shfl_xor(v, 1, 64);
    return v;
}
__global__ __launch_bounds__(1024)
void hypercell_batch(
    const float* __restrict__ xs, const float* __restrict__ cond,
    const float* __restrict__ h_c, const float* __restrict__ h_c_hat,
    const float* __restrict__ x2h_w, const float* __restrict__ x2h_b,
    const float* __restrict__ h2h_w, const float* __restrict__ h2h_b,
    const float* __restrict__ zh_w, const float* __restrict__ zh_b,
    const float* __restrict__ zx_w, const float* __restrict__ zx_b,
    const float* __restrict__ zb_w,
    const float* __restrict__ dh_w, const float* __restrict__ dx_w,
    const float* __restrict__ db_w, const float* __restrict__ db_b,
    const float* __restrict__ wh, const float* __restrict__ wx,
    float* __restrict__ out)
{
    __shared__ float h_s[HH];
    __shared__ float hhat_s[ZHH];
    __shared__ float x_s[IN];
    __shared__ float cond_s[IN];
    __shared__ float whh_s[3*HH];
    __shared__ float wxx_s[3*HH];
    __shared__ float ih_s[3*ZHH];
    __shared__ float hh_s[3*ZHH];
    __shared__ float z_s[288];
    const int b = blockIdx.x, tid = threadIdx.x, lane = tid & 63, wv = tid >> 6;
    if (tid < IN)  cond_s[tid] = cond[(size_t)b*IN + tid];
    if (tid < HH)  h_s[tid]    = h_c[(size_t)b*HH + tid];
    if (tid < ZHH) hhat_s[tid] = h_c_hat[(size_t)b*ZHH + tid];
    __syncthreads();
    for (int t = 0; t < TT; ++t) {
        if (tid < IN) x_s[tid] = xs[((size_t)b*TT + t)*IN + tid];
        const float4* h4 = (const float4*)h_s;
        const float4 ha = h4[lane]; const float4 hb = h4[64 + lane];
        {
            const float* wl = wh + (size_t)(wv*96)*HH + lane*4;
            #pragma unroll 4
            for (int i = 0; i < 96; ++i) {
                float p = wred(dot4_(*(const float4*)(wl + (size_t)i*HH), ha)
                             + dot4_(*(const float4*)(wl + (size_t)i*HH + 256), hb));
                if (lane == 0) whh_s[wv*96 + i] = p;
            }
        }
        {
            const float cv = cond_s[lane];
            const float* wbase = x2h_w + (size_t)(wv*24)*576;
            #pragma unroll 2
            for (int i = 0; i < 24; ++i) {
                const float* wr = wbase + (size_t)i*576;
                float p = wred(dot4_(*(const float4*)(wr + lane*4), ha)
                             + dot4_(*(const float4*)(wr + 256 + lane*4), hb) + wr[512 + lane]*cv);
                if (lane == 0) ih_s[wv*24 + i] = p + x2h_b[wv*24 + i];
            }
        }
        {
            const float2 hv = ((const float2*)hhat_s)[lane];
            const float* wbase = h2h_w + (size_t)(wv*24)*ZHH;
            #pragma unroll 4
            for (int i = 0; i < 24; ++i) {
                float2 wq = *(const float2*)(wbase + (size_t)i*ZHH + lane*2);
                float p = wred(wq.x*hv.x + wq.y*hv.y);
                if (lane == 0) hh_s[wv*24 + i] = p + h2h_b[wv*24 + i];
            }
        }
        __syncthreads();
        {
            const float4* x4 = (const float4*)x_s;
            {
                const float4* wr = (const float4*)(wx + (size_t)tid*IN);
                float acc = 0.f;
                #pragma unroll
                for (int j = 0; j < 16; ++j) acc += dot4_(wr[j], x4[j]);
                wxx_s[tid] = acc;
            }
            if (tid < 512) {
                const int r = 1024 + tid;
                const float4* wr = (const float4*)(wx + (size_t)r*IN);
                float acc = 0.f;
                #pragma unroll
                for (int j = 0; j < 16; ++j) acc += dot4_(wr[j], x4[j]);
                wxx_s[r] = acc;
            }
        }
        if (tid < ZHH) {
            const int j = tid;
            float r = sigmoidf_(ih_s[j] + hh_s[j]);
            float g = sigmoidf_(ih_s[ZHH+j] + hh_s[ZHH+j]);
            float n = tanhf(ih_s[2*ZHH+j] + r*hh_s[2*ZHH+j]);
            float hn = n + g*(hhat_s[j] - n);
            hhat_s[j] = hn;
            if (t == TT-1)
                out[(size_t)BB*TT*HH + (size_t)BB*HH + (size_t)b*ZHH + j] = hn;
        }
        __syncthreads();
        {
            const float2 hv = ((const float2*)hhat_s)[lane];
            #pragma unroll 2
            for (int i = 0; i < 18; ++i) {
                const int R = wv*18 + i, kind = R / 96, r96 = R % 96;
                const float* wsrc = (kind == 0) ? zh_w : ((kind == 1) ? zx_w : zb_w);
                float2 wq = *(const float2*)(wsrc + (size_t)r96*ZHH + lane*2);
                float p = wred(wq.x*hv.x + wq.y*hv.y);
                if (lane == 0)
                    z_s[R] = p + ((kind == 0) ? zh_b[r96] : ((kind == 1) ? zx_b[r96] : 0.f));
            }
        }
        __syncthreads();
        if (tid < HH) {
            const int h = tid;
            const float* dsrc[3] = { dh_w, dx_w, db_w };
            float dv[3][3];
            #pragma unroll
            for (int kind = 0; kind < 3; ++kind)
                #pragma unroll
                for (int l = 0; l < 3; ++l) {
                    const float4* wr = (const float4*)(dsrc[kind] + ((size_t)l*HH + h)*32);
                    const float4* zp = (const float4*)&z_s[kind*96 + l*32];
                    float acc = 0.f;
                    #pragma unroll
                    for (int j = 0; j < 8; ++j) acc += dot4_(wr[j], zp[j]);
                    dv[kind][l] = acc;
                }
            float whh0 = whh_s[h], whh1 = whh_s[HH+h], whh2 = whh_s[2*HH+h];
            float wxx0 = wxx_s[h], wxx1 = wxx_s[HH+h], wxx2 = wxx_s[2*HH+h];
            float db0 = dv[2][0] + db_b[h], db1 = dv[2][1] + db_b[HH+h], db2 = dv[2][2] + db_b[2*HH+h];
            float r0 = sigmoidf_(dv[0][0]*whh0 + dv[1][0]*wxx0 + db0);
            float g0 = sigmoidf_(dv[0][1]*whh1 + dv[1][1]*wxx1 + db1);
            float n0 = tanhf(r0*dv[0][2]*whh2 + dv[1][2]*wxx2 + db2);
            float hold = h_s[h];
            float hnew = n0 + g0*(hold - n0);
            h_s[h] = hnew;
            out[((size_t)b*TT + t)*HH + h] = hnew;
            if (t == TT-1) out[(size_t)BB*TT*HH + (size_t)b*HH + h] = hnew;
        }
        __syncthreads();
    }
}

extern "C" void kernel_launch(void* const* d_in, const int* in_sizes, int n_in,
                              void* d_out, int out_size, void* d_ws, size_t ws_size,
                              hipStream_t stream) {
    const float* xs      = (const float*)d_in[0];
    const float* cond    = (const float*)d_in[1];
    const float* h_c     = (const float*)d_in[2];
    const float* h_c_hat = (const float*)d_in[3];
    const float* x2h_w   = (const float*)d_in[4];
    const float* x2h_b   = (const float*)d_in[5];
    const float* h2h_w   = (const float*)d_in[6];
    const float* h2h_b   = (const float*)d_in[7];
    const float* zh_w    = (const float*)d_in[8];
    const float* zh_b    = (const float*)d_in[9];
    const float* zx_w    = (const float*)d_in[10];
    const float* zx_b    = (const float*)d_in[11];
    const float* zb_w    = (const float*)d_in[12];
    const float* dh_w    = (const float*)d_in[13];
    const float* dx_w    = (const float*)d_in[14];
    const float* db_w    = (const float*)d_in[15];
    const float* db_b    = (const float*)d_in[16];
    const float* wh      = (const float*)d_in[17];
    const float* wx      = (const float*)d_in[18];
    float* out = (float*)d_out;

    if (ws_size >= (size_t)WS_NOX2H) {
        char* wsb = (char*)d_ws;
        const int full = (ws_size >= (size_t)WS_FULL) ? 1 : 0;
        const int xtra = (ws_size >= (size_t)WS_XTRA) ? 1 : 0;
        hipMemsetAsync(wsb + OFF_FLAG, 0, 8192, stream);
        hipLaunchKernelGGL(pack_w, dim3(654), dim3(256), 0, stream,
                           wh, wx, dh_w, dx_w, db_w, x2h_w, h2h_w,
                           zh_w, zx_w, zb_w, full, xtra, wsb);
        if (xtra) {
            hipLaunchKernelGGL((hypercell_s<1,1>), dim3(512), dim3(NT), 0, stream,
                               xs, cond, h_c, h_c_hat, x2h_w, x2h_b, h2h_w, h2h_b,
                               zh_w, zh_b, zx_w, zx_b, zb_w, db_b, wsb, out);
        } else if (full) {
            hipLaunchKernelGGL((hypercell_s<1,0>), dim3(512), dim3(NT), 0, stream,
                               xs, cond, h_c, h_c_hat, x2h_w, x2h_b, h2h_w, h2h_b,
                               zh_w, zh_b, zx_w, zx_b, zb_w, db_b, wsb, out);
        } else {
            hipLaunchKernelGGL((hypercell_s<0,0>), dim3(512), dim3(NT), 0, stream,
                               xs, cond, h_c, h_c_hat, x2h_w, x2h_b, h2h_w, h2h_b,
                               zh_w, zh_b, zx_w, zx_b, zb_w, db_b, wsb, out);
        }
    } else {
        hipLaunchKernelGGL(hypercell_batch, dim3(BB), dim3(1024), 0, stream,
                           xs, cond, h_c, h_c_hat, x2h_w, x2h_b, h2h_w, h2h_b,
                           zh_w, zh_b, zx_w, zx_b, zb_w, dh_w, dx_w, db_w, db_b,
                           wh, wx, out);
    }
}

// Round 10
// 8870.865 us; speedup vs baseline: 2.0052x; 1.7873x over previous
//
#include <hip/hip_runtime.h>
#include <math.h>

// Problem constants
#define BB  64
#define TT  512
#define IN  64
#define HH  512
#define ZHH 128
#define NT  1024

// ---- ws layout (byte offsets) ----
#define OFF_EXIH   0u          // f32 [64][768]
#define OFF_EXH    196608u     // f32 [64][512]
#define OFF_FLAG   327680u     // 2*64 ints, 64B stride
#define OFF_WH     335872u     // bf16 [q<4][k8<64][384][8]
#define OFF_WX     1908736u    // bf16 [q<4][k8<8][384][8]
#define OFF_DW     2105344u    // bf16 [q<4][k8<4][1152][8]
#define OFF_X2H    2400256u    // bf16 [q<4][k8<72][96][8]
#define OFF_H2HB   2842624u    // bf16 [q<4][k8<16][96][8]
#define OFF_ZWB    2940928u    // bf16 [k8<16][288][8]
#define WS_NOX2H   2400256u
#define WS_FULL    2842624u
#define WS_XTRA    3014656u

typedef __attribute__((ext_vector_type(2))) float f32x2;

__device__ __forceinline__ float sigmoidf_(float x) {
    return 1.0f / (1.0f + __expf(-x));
}
__device__ __forceinline__ float tanhf_(float x) {
    return 2.0f / (1.0f + __expf(-2.0f * x)) - 1.0f;
}
__device__ __forceinline__ float bflo(unsigned u) { return __uint_as_float(u << 16); }
__device__ __forceinline__ float bfhi(unsigned u) { return __uint_as_float(u & 0xffff0000u); }
__device__ __forceinline__ unsigned short f2bf(float f) {
    unsigned u = __float_as_uint(f);
    return (unsigned short)((u + 0x7fffu + ((u >> 16) & 1u)) >> 16);
}
// packed dot of 8 bf16 weights x 8 f32 acts; accumulates into f32x2 so the
// compiler emits v_pk_fma_f32 (2 MACs/inst): 12 VALU ops per 8 MACs vs 16 scalar.
__device__ __forceinline__ f32x2 dotbf8p(uint4 U, float4 a, float4 b, f32x2 acc) {
    acc += (f32x2){bflo(U.x), bfhi(U.x)} * (f32x2){a.x, a.y};
    acc += (f32x2){bflo(U.y), bfhi(U.y)} * (f32x2){a.z, a.w};
    acc += (f32x2){bflo(U.z), bfhi(U.z)} * (f32x2){b.x, b.y};
    acc += (f32x2){bflo(U.w), bfhi(U.w)} * (f32x2){b.z, b.w};
    return acc;
}
__device__ __forceinline__ float dot4_(const float4 a, const float4 b) {
    return a.x*b.x + a.y*b.y + a.z*b.z + a.w*b.w;
}
__device__ __forceinline__ uint4 packbf8(const float* s) {
    float4 a = *(const float4*)s;
    float4 c = *(const float4*)(s + 4);
    uint4 q;
    q.x = (unsigned)f2bf(a.x) | ((unsigned)f2bf(a.y) << 16);
    q.y = (unsigned)f2bf(a.z) | ((unsigned)f2bf(a.w) << 16);
    q.z = (unsigned)f2bf(c.x) | ((unsigned)f2bf(c.y) << 16);
    q.w = (unsigned)f2bf(c.z) | ((unsigned)f2bf(c.w) << 16);
    return q;
}

// ---------- pre-pass: quarter-sliced bf16 repack (identical to R5) ----------
__global__ __launch_bounds__(256)
void pack_w(const float* __restrict__ wh, const float* __restrict__ wx,
            const float* __restrict__ dh_w, const float* __restrict__ dx_w,
            const float* __restrict__ db_w, const float* __restrict__ x2h_w,
            const float* __restrict__ h2h_w, const float* __restrict__ zh_w,
            const float* __restrict__ zx_w, const float* __restrict__ zb_w,
            int packX2H, int packHZ, char* __restrict__ wsb)
{
    const int u = blockIdx.x * 256 + threadIdx.x;
    if (u < 98304) {                                   // WH
        int q = u / 24576, r1 = u % 24576, k8 = r1 / 384, rr = r1 % 384;
        int g = rr >> 7, hl = rr & 127, h = q*128 + hl;
        ((uint4*)(wsb + OFF_WH))[u] = packbf8(wh + ((size_t)(g*512 + h))*512 + k8*8);
    } else if (u < 110592) {                           // WX
        int v = u - 98304;
        int q = v / 3072, r1 = v % 3072, k8 = r1 / 384, rr = r1 % 384;
        int g = rr >> 7, hl = rr & 127, h = q*128 + hl;
        ((uint4*)(wsb + OFF_WX))[v] = packbf8(wx + ((size_t)(g*512 + h))*64 + k8*8);
    } else if (u < 129024) {                           // DW
        int v = u - 110592;
        int q = v / 4608, r1 = v % 4608, k8 = r1 / 1152, rr = r1 % 1152;
        int u9 = rr >> 7, hl = rr & 127, h = q*128 + hl;
        int kind = u9 / 3, l = u9 - kind*3;
        const float* dsrc = (kind == 0) ? dh_w : ((kind == 1) ? dx_w : db_w);
        ((uint4*)(wsb + OFF_DW))[v] = packbf8(dsrc + ((size_t)(l*512) + h)*32 + k8*8);
    } else if (u < 156672) {                           // X2H
        if (!packX2H) return;
        int v = u - 129024;
        int q = v / 6912, r1 = v % 6912, k8 = r1 / 96, rr = r1 % 96;
        int g = rr >> 5, zz = rr & 31, j = g*128 + q*32 + zz;
        ((uint4*)(wsb + OFF_X2H))[v] = packbf8(x2h_w + (size_t)j*576 + k8*8);
    } else if (u < 162816) {                           // H2HB
        if (!packHZ) return;
        int v = u - 156672;
        int q = v / 1536, r1 = v % 1536, k8 = r1 / 96, rr = r1 % 96;
        int g = rr >> 5, zz = rr & 31, j = g*128 + q*32 + zz;
        ((uint4*)(wsb + OFF_H2HB))[v] = packbf8(h2h_w + (size_t)j*128 + k8*8);
    } else if (u < 167424) {                           // ZWB
        if (!packHZ) return;
        int v = u - 162816;
        int k8 = v / 288, r = v % 288;
        const float* src = (r < 96) ? (zh_w + (size_t)r*128)
                         : ((r < 192) ? (zx_w + (size_t)(r - 96)*128)
                                      : (zb_w + (size_t)(r - 192)*128));
        ((uint4*)(wsb + OFF_ZWB))[v] = packbf8(src + k8*8);
    }
}

// ---------- main: 256 WGs = 64 batches x 4 row-quarters, 1024 thr ----------
// EXACT R5 structure (proven 9735 us, FETCH 106 MB); only dot internals changed
// to packed f32x2 accumulation. b=blk&63, q=blk>>6 (siblings same XCD @ 1 WG/CU).
template<int X2HP, int HZP>
__global__ __launch_bounds__(NT)
void hypercell_q(
    const float* __restrict__ xs, const float* __restrict__ cond,
    const float* __restrict__ h_c, const float* __restrict__ h_c_hat,
    const float* __restrict__ x2h_w, const float* __restrict__ x2h_b,
    const float* __restrict__ h2h_w, const float* __restrict__ h2h_b,
    const float* __restrict__ zh_w, const float* __restrict__ zh_b,
    const float* __restrict__ zx_w, const float* __restrict__ zx_b,
    const float* __restrict__ zb_w, const float* __restrict__ db_b,
    char* __restrict__ wsb, float* __restrict__ out)
{
    __shared__ __align__(16) float sh_h[512];
    __shared__ __align__(16) float sh_hat[128];
    __shared__ __align__(16) float sh_x[64];
    __shared__ __align__(16) float sh_c[64];
    __shared__ __align__(16) float sh_z[288];
    __shared__ float sh_whhp[768];   // [half][384]
    __shared__ float sh_wxx[384];
    __shared__ float sh_ihp[192];    // [half][96]
    __shared__ float sh_d[1152];
    __shared__ float sh_bih[96];
    __shared__ float sh_bhh[96];
    __shared__ float sh_bz[288];
    __shared__ float sh_bdb[384];

    const int b   = blockIdx.x & 63;     // batch
    const int q   = blockIdx.x >> 6;     // row quarter
    const int tid = threadIdx.x;

    const uint4* WHq   = (const uint4*)(wsb + OFF_WH)   + q*24576;
    const uint4* WXq   = (const uint4*)(wsb + OFF_WX)   + q*3072;
    const uint4* DWq   = (const uint4*)(wsb + OFF_DW)   + q*4608;
    const uint4* X2Hq  = (const uint4*)(wsb + OFF_X2H)  + q*6912;
    const uint4* H2HBq = (const uint4*)(wsb + OFF_H2HB) + q*1536;
    const uint4* ZWB   = (const uint4*)(wsb + OFF_ZWB);

    float* exch_ihhh = (float*)(wsb + OFF_EXIH) + (size_t)b*768;
    float* exch_h    = (float*)(wsb + OFF_EXH)  + (size_t)b*512;
    int* flagA = (int*)(wsb + OFF_FLAG + (size_t)b*64);
    int* flagB = (int*)(wsb + OFF_FLAG + 4096 + (size_t)b*64);

    // ---- init staging ----
    if (tid < 96) {
        int j = (tid >> 5)*128 + q*32 + (tid & 31);
        sh_bih[tid] = x2h_b[j];
        sh_bhh[tid] = h2h_b[j];
    }
    if (tid < 288) sh_bz[tid] = (tid < 96) ? zh_b[tid]
                              : ((tid < 192) ? zx_b[tid - 96] : 0.f);
    if (tid < 384) {
        int l = tid >> 7, hl = tid & 127;
        sh_bdb[tid] = db_b[l*512 + q*128 + hl];
    }
    if (tid < 512) sh_h[tid] = h_c[(size_t)b*512 + tid];
    if (tid < 128) sh_hat[tid] = h_c_hat[(size_t)b*128 + tid];
    if (tid < 64) {
        sh_c[tid] = cond[(size_t)b*64 + tid];
        sh_x[tid] = xs[(size_t)b*TT*IN + tid];
    }
    __syncthreads();

    for (int t = 0; t < TT; ++t) {
        const float4* h4   = (const float4*)sh_h;
        const float4* hat4 = (const float4*)sh_hat;
        const float4* c4   = (const float4*)sh_c;

        // ===== Phase A: K-split sliced matvecs on old state =====
        if (tid < 768) {
            // whh half-row: rr in [0,384), half selects K 0..255 / 256..511
            const int half = (tid >= 384);
            const int rr = half ? (tid - 384) : tid;
            const uint4* W0 = WHq + (half ? 32*384 : 0) + rr;
            const float4* hblk = h4 + half*64;
            f32x2 a0 = {0.f, 0.f};
            #pragma unroll 8
            for (int k8 = 0; k8 < 32; ++k8)
                a0 = dotbf8p(W0[k8*384], hblk[2*k8], hblk[2*k8 + 1], a0);
            sh_whhp[half*384 + rr] = a0.x + a0.y;
            if (!half) {
                // wxx full row (K=64)
                f32x2 a1 = {0.f, 0.f};
                const uint4* X0 = WXq + rr;
                const float4* x4 = (const float4*)sh_x;
                #pragma unroll
                for (int k8 = 0; k8 < 8; ++k8)
                    a1 = dotbf8p(X0[k8*384], x4[2*k8], x4[2*k8 + 1], a1);
                sh_wxx[rr] = a1.x + a1.y;
            }
        } else if (tid < 960) {
            // ih half-row: rr in [0,96); half0 k8 0..35, half1 k8 36..71
            const int u = tid - 768;
            const int half = (u >= 96);
            const int rr = half ? (u - 96) : u;
            float res;
            if (X2HP) {
                f32x2 acc = {0.f, 0.f};
                const uint4* W0 = X2Hq + rr;
                if (!half) {
                    #pragma unroll 4
                    for (int k8 = 0; k8 < 36; ++k8)
                        acc = dotbf8p(W0[k8*96], h4[2*k8], h4[2*k8 + 1], acc);
                } else {
                    #pragma unroll 4
                    for (int k8 = 36; k8 < 64; ++k8)
                        acc = dotbf8p(W0[k8*96], h4[2*k8], h4[2*k8 + 1], acc);
                    #pragma unroll
                    for (int k8 = 64; k8 < 72; ++k8)
                        acc = dotbf8p(W0[k8*96], c4[2*(k8-64)], c4[2*(k8-64) + 1], acc);
                }
                res = acc.x + acc.y;
            } else {
                float a = 0.f;
                const int j = (rr >> 5)*128 + q*32 + (rr & 31);
                const float4* wr = (const float4*)(x2h_w + (size_t)j*576);
                if (!half) {
                    #pragma unroll 8
                    for (int k4 = 0; k4 < 72; ++k4) a += dot4_(wr[k4], h4[k4]);
                } else {
                    #pragma unroll 8
                    for (int k4 = 72; k4 < 128; ++k4) a += dot4_(wr[k4], h4[k4]);
                    #pragma unroll
                    for (int k4 = 128; k4 < 144; ++k4) a += dot4_(wr[k4], c4[k4 - 128]);
                }
                res = a;
            }
            sh_ihp[half*96 + rr] = (half ? 0.f : sh_bih[rr]) + res;
        } else {
            // hh rows (K=128), direct exch store
            const int t3 = tid - 960;
            #pragma unroll
            for (int p = 0; p < 2; ++p) {
                const int rr = t3 + 64*p;
                if (rr < 96) {
                    const int j = (rr >> 5)*128 + q*32 + (rr & 31);
                    float a = sh_bhh[rr];
                    if (HZP) {
                        f32x2 acc = {0.f, 0.f};
                        const uint4* W = H2HBq + rr;
                        #pragma unroll 8
                        for (int k8 = 0; k8 < 16; ++k8)
                            acc = dotbf8p(W[k8*96], hat4[2*k8], hat4[2*k8 + 1], acc);
                        a += acc.x + acc.y;
                    } else {
                        const float4* wr = (const float4*)(h2h_w + (size_t)j*128);
                        #pragma unroll 8
                        for (int k4 = 0; k4 < 32; ++k4) a += dot4_(wr[k4], hat4[k4]);
                    }
                    __hip_atomic_store(&exch_ihhh[384 + j], a, __ATOMIC_RELAXED, __HIP_MEMORY_SCOPE_AGENT);
                }
            }
        }
        __syncthreads();
        // combine ih halves, publish
        if (tid < 96) {
            const int j = (tid >> 5)*128 + q*32 + (tid & 31);
            __hip_atomic_store(&exch_ihhh[j], sh_ihp[tid] + sh_ihp[96 + tid],
                               __ATOMIC_RELAXED, __HIP_MEMORY_SCOPE_AGENT);
        }
        // ===== sync1 =====
        asm volatile("s_waitcnt vmcnt(0)" ::: "memory");
        __syncthreads();
        if (tid == 0) {
            __hip_atomic_fetch_add(flagA, 1, __ATOMIC_RELAXED, __HIP_MEMORY_SCOPE_AGENT);
            while (__hip_atomic_load(flagA, __ATOMIC_RELAXED, __HIP_MEMORY_SCOPE_AGENT) < 4*(t+1))
                __builtin_amdgcn_s_sleep(1);
        }
        __syncthreads();

        // ===== Phase B: hyper-GRU elementwise (reads exch direct) =====
        if (tid < 128) {
            const int j = tid;
            float i_r = __hip_atomic_load(&exch_ihhh[j],       __ATOMIC_RELAXED, __HIP_MEMORY_SCOPE_AGENT);
            float i_i = __hip_atomic_load(&exch_ihhh[128 + j], __ATOMIC_RELAXED, __HIP_MEMORY_SCOPE_AGENT);
            float i_n = __hip_atomic_load(&exch_ihhh[256 + j], __ATOMIC_RELAXED, __HIP_MEMORY_SCOPE_AGENT);
            float h_r = __hip_atomic_load(&exch_ihhh[384 + j], __ATOMIC_RELAXED, __HIP_MEMORY_SCOPE_AGENT);
            float h_i = __hip_atomic_load(&exch_ihhh[512 + j], __ATOMIC_RELAXED, __HIP_MEMORY_SCOPE_AGENT);
            float h_n = __hip_atomic_load(&exch_ihhh[640 + j], __ATOMIC_RELAXED, __HIP_MEMORY_SCOPE_AGENT);
            float rg = sigmoidf_(i_r + h_r);
            float gg = sigmoidf_(i_i + h_i);
            float nn = tanhf_(i_n + rg * h_n);
            float hn = nn + gg * (sh_hat[j] - nn);
            sh_hat[j] = hn;
            if (t == TT - 1 && q == 0)
                __builtin_nontemporal_store(hn,
                    &out[(size_t)BB*TT*HH + (size_t)BB*HH + (size_t)b*ZHH + j]);
        } else if (tid >= 128 && tid < 192 && t + 1 < TT) {
            sh_x[tid - 128] = xs[((size_t)b*TT + t + 1)*IN + (tid - 128)];
        }
        __syncthreads();

        // ===== z = hhat_new @ zw.T (288 rows, K=128) =====
        if (tid < 288) {
            float base = sh_bz[tid];
            const float4* nhat4 = (const float4*)sh_hat;
            float res;
            if (HZP) {
                f32x2 acc = {0.f, 0.f};
                const uint4* W = ZWB + tid;
                #pragma unroll 8
                for (int k8 = 0; k8 < 16; ++k8)
                    acc = dotbf8p(W[k8*288], nhat4[2*k8], nhat4[2*k8 + 1], acc);
                res = acc.x + acc.y;
            } else {
                float a = 0.f;
                const float* src = (tid < 96) ? (zh_w + (size_t)tid*128)
                                 : ((tid < 192) ? (zx_w + (size_t)(tid - 96)*128)
                                                : (zb_w + (size_t)(tid - 192)*128));
                const float4* W = (const float4*)src;
                #pragma unroll 8
                for (int k4 = 0; k4 < 32; ++k4) a += dot4_(W[k4], nhat4[k4]);
                res = a;
            }
            sh_z[tid] = base + res;
        }
        __syncthreads();

        // ===== d quarter (1152 rows, K=32, bf16) =====
        #pragma unroll
        for (int rp = 0; rp < 2; ++rp) {
            const int rr = tid + rp*NT;
            if (rr < 1152) {
                const int u9 = rr >> 7;
                const int kind = u9 / 3, l = u9 - kind*3;
                const uint4* W = DWq + rr;
                const float4* Z = (const float4*)(&sh_z[kind*96 + l*32]);
                f32x2 acc = {0.f, 0.f};
                #pragma unroll
                for (int k8 = 0; k8 < 4; ++k8)
                    acc = dotbf8p(W[k8*1152], Z[2*k8], Z[2*k8 + 1], acc);
                sh_d[rr] = acc.x + acc.y;
            }
        }
        __syncthreads();

        // ===== gates -> h_new quarter =====
        if (tid < 128) {
            const int hl = tid, hg = q*128 + hl;
            float whh0 = sh_whhp[hl]       + sh_whhp[384 + hl];
            float whh1 = sh_whhp[128 + hl] + sh_whhp[512 + hl];
            float whh2 = sh_whhp[256 + hl] + sh_whhp[640 + hl];
            float wxx0 = sh_wxx[hl], wxx1 = sh_wxx[128 + hl], wxx2 = sh_wxx[256 + hl];
            float dh0 = sh_d[hl],       dh1 = sh_d[128 + hl], dh2 = sh_d[256 + hl];
            float dx0 = sh_d[384 + hl], dx1 = sh_d[512 + hl], dx2 = sh_d[640 + hl];
            float db0 = sh_d[768 + hl]  + sh_bdb[hl];
            float db1 = sh_d[896 + hl]  + sh_bdb[128 + hl];
            float db2 = sh_d[1024 + hl] + sh_bdb[256 + hl];
            float r0 = sigmoidf_(dh0*whh0 + dx0*wxx0 + db0);
            float g0 = sigmoidf_(dh1*whh1 + dx1*wxx1 + db1);
            float n0 = tanhf_(r0*dh2*whh2 + dx2*wxx2 + db2);
            float hold = sh_h[hg];
            float hnew = n0 + g0*(hold - n0);
            __builtin_nontemporal_store(hnew, &out[((size_t)b*TT + t)*HH + hg]);
            if (t == TT - 1)
                __builtin_nontemporal_store(hnew, &out[(size_t)BB*TT*HH + (size_t)b*512 + hg]);
            __hip_atomic_store(&exch_h[hg], hnew, __ATOMIC_RELAXED, __HIP_MEMORY_SCOPE_AGENT);
        }
        // ===== sync2 =====
        asm volatile("s_waitcnt vmcnt(0)" ::: "memory");
        __syncthreads();
        if (tid == 0) {
            __hip_atomic_fetch_add(flagB, 1, __ATOMIC_RELAXED, __HIP_MEMORY_SCOPE_AGENT);
            while (__hip_atomic_load(flagB, __ATOMIC_RELAXED, __HIP_MEMORY_SCOPE_AGENT) < 4*(t+1))
                __builtin_amdgcn_s_sleep(1);
        }
        __syncthreads();
        if (tid < 512)
            sh_h[tid] = __hip_atomic_load(&exch_h[tid], __ATOMIC_RELAXED, __HIP_MEMORY_SCOPE_AGENT);
        __syncthreads();
    }
}

// ---------- fp32 fallback (proven; used only if ws too small) ----------
__device__ __forceinline__ float wred(float v) {
    v += __shfl_xor(v, 32, 64); v += __shfl_xor(v, 16, 64); v += __shfl_xor(v, 8, 64);
    v += __shfl_xor(v, 4, 64);  v += __shfl_xor(v, 2, 64);  v += __shfl_xor(v, 1, 64);
    return v;
}
__global__ __launch_bounds__(1024)
void hypercell_batch(
    const float* __restrict__ xs, const float* __restrict__ cond,
    const float* __restrict__ h_c, const float* __restrict__ h_c_hat,
    const float* __restrict__ x2h_w, const float* __restrict__ x2h_b,
    const float* __restrict__ h2h_w, const float* __restrict__ h2h_b,
    const float* __restrict__ zh_w, const float* __restrict__ zh_b,
    const float* __restrict__ zx_w, const float* __restrict__ zx_b,
    const float* __restrict__ zb_w,
    const float* __restrict__ dh_w, const float* __restrict__ dx_w,
    const float* __restrict__ db_w, const float* __restrict__ db_b,
    const float* __restrict__ wh, const float* __restrict__ wx,
    float* __restrict__ out)
{
    __shared__ float h_s[HH];
    __shared__ float hhat_s[ZHH];
    __shared__ float x_s[IN];
    __shared__ float cond_s[IN];
    __shared__ float whh_s[3*HH];
    __shared__ float wxx_s[3*HH];
    __shared__ float ih_s[3*ZHH];
    __shared__ float hh_s[3*ZHH];
    __shared__ float z_s[288];
    const int b = blockIdx.x, tid = threadIdx.x, lane = tid & 63, wv = tid >> 6;
    if (tid < IN)  cond_s[tid] = cond[(size_t)b*IN + tid];
    if (tid < HH)  h_s[tid]    = h_c[(size_t)b*HH + tid];
    if (tid < ZHH) hhat_s[tid] = h_c_hat[(size_t)b*ZHH + tid];
    __syncthreads();
    for (int t = 0; t < TT; ++t) {
        if (tid < IN) x_s[tid] = xs[((size_t)b*TT + t)*IN + tid];
        const float4* h4 = (const float4*)h_s;
        const float4 ha = h4[lane]; const float4 hb = h4[64 + lane];
        {
            const float* wl = wh + (size_t)(wv*96)*HH + lane*4;
            #pragma unroll 4
            for (int i = 0; i < 96; ++i) {
                float p = wred(dot4_(*(const float4*)(wl + (size_t)i*HH), ha)
                             + dot4_(*(const float4*)(wl + (size_t)i*HH + 256), hb));
                if (lane == 0) whh_s[wv*96 + i] = p;
            }
        }
        {
            const float cv = cond_s[lane];
            const float* wbase = x2h_w + (size_t)(wv*24)*576;
            #pragma unroll 2
            for (int i = 0; i < 24; ++i) {
                const float* wr = wbase + (size_t)i*576;
                float p = wred(dot4_(*(const float4*)(wr + lane*4), ha)
                             + dot4_(*(const float4*)(wr + 256 + lane*4), hb) + wr[512 + lane]*cv);
                if (lane == 0) ih_s[wv*24 + i] = p + x2h_b[wv*24 + i];
            }
        }
        {
            const float2 hv = ((const float2*)hhat_s)[lane];
            const float* wbase = h2h_w + (size_t)(wv*24)*ZHH;
            #pragma unroll 4
            for (int i = 0; i < 24; ++i) {
                float2 wq = *(const float2*)(wbase + (size_t)i*ZHH + lane*2);
                float p = wred(wq.x*hv.x + wq.y*hv.y);
                if (lane == 0) hh_s[wv*24 + i] = p + h2h_b[wv*24 + i];
            }
        }
        __syncthreads();
        {
            const float4* x4 = (const float4*)x_s;
            {
                const float4* wr = (const float4*)(wx + (size_t)tid*IN);
                float acc = 0.f;
                #pragma unroll
                for (int j = 0; j < 16; ++j) acc += dot4_(wr[j], x4[j]);
                wxx_s[tid] = acc;
            }
            if (tid < 512) {
                const int r = 1024 + tid;
                const float4* wr = (const float4*)(wx + (size_t)r*IN);
                float acc = 0.f;
                #pragma unroll
                for (int j = 0; j < 16; ++j) acc += dot4_(wr[j], x4[j]);
                wxx_s[r] = acc;
            }
        }
        if (tid < ZHH) {
            const int j = tid;
            float r = sigmoidf_(ih_s[j] + hh_s[j]);
            float g = sigmoidf_(ih_s[ZHH+j] + hh_s[ZHH+j]);
            float n = tanhf(ih_s[2*ZHH+j] + r*hh_s[2*ZHH+j]);
            float hn = n + g*(hhat_s[j] - n);
            hhat_s[j] = hn;
            if (t == TT-1)
                out[(size_t)BB*TT*HH + (size_t)BB*HH + (size_t)b*ZHH + j] = hn;
        }
        __syncthreads();
        {
            const float2 hv = ((const float2*)hhat_s)[lane];
            #pragma unroll 2
            for (int i = 0; i < 18; ++i) {
                const int R = wv*18 + i, kind = R / 96, r96 = R % 96;
                const float* wsrc = (kind == 0) ? zh_w : ((kind == 1) ? zx_w : zb_w);
                float2 wq = *(const float2*)(wsrc + (size_t)r96*ZHH + lane*2);
                float p = wred(wq.x*hv.x + wq.y*hv.y);
                if (lane == 0)
                    z_s[R] = p + ((kind == 0) ? zh_b[r96] : ((kind == 1) ? zx_b[r96] : 0.f));
            }
        }
        __syncthreads();
        if (tid < HH) {
            const int h = tid;
            const float* dsrc[3] = { dh_w, dx_w, db_w };
            float dv[3][3];
            #pragma unroll
            for (int kind = 0; kind < 3; ++kind)
                #pragma unroll
                for (int l = 0; l < 3; ++l) {
                    const float4* wr = (const float4*)(dsrc[kind] + ((size_t)l*HH + h)*32);
                    const float4* zp = (const float4*)&z_s[kind*96 + l*32];
                    float acc = 0.f;
                    #pragma unroll
                    for (int j = 0; j < 8; ++j) acc += dot4_(wr[j], zp[j]);
                    dv[kind][l] = acc;
                }
            float whh0 = whh_s[h], whh1 = whh_s[HH+h], whh2 = whh_s[2*HH+h];
            float wxx0 = wxx_s[h], wxx1 = wxx_s[HH+h], wxx2 = wxx_s[2*HH+h];
            float db0 = dv[2][0] + db_b[h], db1 = dv[2][1] + db_b[HH+h], db2 = dv[2][2] + db_b[2*HH+h];
            float r0 = sigmoidf_(dv[0][0]*whh0 + dv[1][0]*wxx0 + db0);
            float g0 = sigmoidf_(dv[0][1]*whh1 + dv[1][1]*wxx1 + db1);
            float n0 = tanhf(r0*dv[0][2]*whh2 + dv[1][2]*wxx2 + db2);
            float hold = h_s[h];
            float hnew = n0 + g0*(hold - n0);
            h_s[h] = hnew;
            out[((size_t)b*TT + t)*HH + h] = hnew;
            if (t == TT-1) out[(size_t)BB*TT*HH + (size_t)b*HH + h] = hnew;
        }
        __syncthreads();
    }
}

extern "C" void kernel_launch(void* const* d_in, const int* in_sizes, int n_in,
                              void* d_out, int out_size, void* d_ws, size_t ws_size,
                              hipStream_t stream) {
    const float* xs      = (const float*)d_in[0];
    const float* cond    = (const float*)d_in[1];
    const float* h_c     = (const float*)d_in[2];
    const float* h_c_hat = (const float*)d_in[3];
    const float* x2h_w   = (const float*)d_in[4];
    const float* x2h_b   = (const float*)d_in[5];
    const float* h2h_w   = (const float*)d_in[6];
    const float* h2h_b   = (const float*)d_in[7];
    const float* zh_w    = (const float*)d_in[8];
    const float* zh_b    = (const float*)d_in[9];
    const float* zx_w    = (const float*)d_in[10];
    const float* zx_b    = (const float*)d_in[11];
    const float* zb_w    = (const float*)d_in[12];
    const float* dh_w    = (const float*)d_in[13];
    const float* dx_w    = (const float*)d_in[14];
    const float* db_w    = (const float*)d_in[15];
    const float* db_b    = (const float*)d_in[16];
    const float* wh      = (const float*)d_in[17];
    const float* wx      = (const float*)d_in[18];
    float* out = (float*)d_out;

    if (ws_size >= (size_t)WS_NOX2H) {
        char* wsb = (char*)d_ws;
        const int full = (ws_size >= (size_t)WS_FULL) ? 1 : 0;
        const int xtra = (ws_size >= (size_t)WS_XTRA) ? 1 : 0;
        hipMemsetAsync(wsb + OFF_FLAG, 0, 8192, stream);
        hipLaunchKernelGGL(pack_w, dim3(654), dim3(256), 0, stream,
                           wh, wx, dh_w, dx_w, db_w, x2h_w, h2h_w,
                           zh_w, zx_w, zb_w, full, xtra, wsb);
        if (xtra) {
            hipLaunchKernelGGL((hypercell_q<1,1>), dim3(256), dim3(NT), 0, stream,
                               xs, cond, h_c, h_c_hat, x2h_w, x2h_b, h2h_w, h2h_b,
                               zh_w, zh_b, zx_w, zx_b, zb_w, db_b, wsb, out);
        } else if (full) {
            hipLaunchKernelGGL((hypercell_q<1,0>), dim3(256), dim3(NT), 0, stream,
                               xs, cond, h_c, h_c_hat, x2h_w, x2h_b, h2h_w, h2h_b,
                               zh_w, zh_b, zx_w, zx_b, zb_w, db_b, wsb, out);
        } else {
            hipLaunchKernelGGL((hypercell_q<0,0>), dim3(256), dim3(NT), 0, stream,
                               xs, cond, h_c, h_c_hat, x2h_w, x2h_b, h2h_w, h2h_b,
                               zh_w, zh_b, zx_w, zx_b, zb_w, db_b, wsb, out);
        }
    } else {
        hipLaunchKernelGGL(hypercell_batch, dim3(BB), dim3(1024), 0, stream,
                           xs, cond, h_c, h_c_hat, x2h_w, x2h_b, h2h_w, h2h_b,
                           zh_w, zh_b, zx_w, zx_b, zb_w, dh_w, dx_w, db_w, db_b,
                           wh, wx, out);
    }
}